// Round 8
// baseline (1708.007 us; speedup 1.0000x reference)
//
#include <hip/hip_runtime.h>
#include <math.h>

// ---------------------------------------------------------------------------
// 2-layer GCN:  out = gcn(relu(gcn(x, W1, b1)), W2, b2)
// gcn(x,W,b)[c] = dinv[c] * ( y[c] + sum_{edges r->c} y[r] ) + b
//   where y[r] = dinv[r] * (x[r] @ W),  dinv = rsqrt(1 + indeg)
// No CSR: edges bucketed by target (2-level, line-granular); aggregation
// accumulates into a per-bucket LDS fp32 tile via ds_add (no global atomics).
// Features stored permuted (16j+r -> 8r+j per 128-half) so LDS atomics are
// bank-conflict-free; permutation is consistent across GEMM stores, wt2, and
// bias; final fp32 write un-permutes.
// ---------------------------------------------------------------------------

typedef _Float16 h8 __attribute__((ext_vector_type(8)));
typedef _Float16 h4 __attribute__((ext_vector_type(4)));
typedef float    f32x4 __attribute__((ext_vector_type(4)));

#define NPB    98     // nodes per fine bucket
#define NB2    512    // fine buckets (max)
#define FBPC   64     // fine buckets per coarse
#define NB1    8      // coarse buckets (max)
#define NST    132    // LDS accumulator row stride (floats); 132%32=4 spreads banks
#define B1SLOT 128
#define B2SLOT 64

__device__ __forceinline__ int permf(int f) {   // within 128-half: 16j+r -> 8r+j
    int half = f & ~127, h = f & 127;
    return half | ((h & 15) << 3) | (h >> 4);
}

// init: zero deg (+ small counters) and prep weights/bias
__global__ void k_init(int* __restrict__ deg, int* __restrict__ gcur1,
                       int* __restrict__ gcur2, int* __restrict__ govf, int N,
                       const float* __restrict__ W1, const float* __restrict__ W2,
                       const float* __restrict__ b1,
                       _Float16* __restrict__ wt1, _Float16* __restrict__ wt2,
                       float* __restrict__ bperm1,
                       int K, int n1, int n2, int zb)
{
    int tid = threadIdx.x;
    if ((int)blockIdx.x < zb) {
        int i = blockIdx.x * 256 + tid;
        if (i < N) deg[i] = 0;
        if (blockIdx.x == 0) {
            if (tid < NB1) gcur1[tid] = 0;
            if (tid < 2) govf[tid] = 0;
        }
        if (blockIdx.x >= 1 && blockIdx.x <= 2) {
            int g = (blockIdx.x - 1) * 256 + tid;
            if (g < NB2) gcur2[g] = 0;
        }
        if (blockIdx.x == 3 && tid < n1) bperm1[permf(tid)] = b1[tid];
    } else {
        int i = (blockIdx.x - zb) * 256 + tid;
        int c1 = K * n1;
        if (i < c1) {
            int k = i / n1, n = i % n1;
            wt1[(long)n * K + k] = (_Float16)W1[i];           // k order = orig (x unpermuted)
        } else if (i < c1 + K * n2) {
            int j = i - c1;
            int k = j / n2, n = j % n2;
            wt2[(long)n * K + permf(k)] = (_Float16)W2[j];    // k order = permuted (h16)
        }
    }
}

// level-1: 8-way bucket by col range + degree histogram (LDS chunk flushes)
__global__ __launch_bounds__(256) void k_bucket1(
    const int* __restrict__ row, const int* __restrict__ col, int E, int bdiv1,
    int* __restrict__ deg, int* __restrict__ gcur1,
    int2* __restrict__ ebuf1, int cap1, int2* __restrict__ ovf1, int* __restrict__ govf)
{
    __shared__ int2 lbuf[NB1][B1SLOT];
    __shared__ int lcnt[NB1], lbase[NB1];
    const int tid = threadIdx.x;
    if (tid < NB1) lcnt[tid] = 0;
    __syncthreads();
    const int stride = gridDim.x * 256;
    for (int base = blockIdx.x * 256; base < E; base += stride) {
        int e = base + tid;
        if (e < E) {
            int2 pr; pr.x = row[e]; pr.y = col[e];
            atomicAdd(&deg[pr.y], 1);
            int bkt = (unsigned)pr.y / (unsigned)bdiv1;
            int ls = atomicAdd(&lcnt[bkt], 1);
            if (ls < B1SLOT) lbuf[bkt][ls] = pr;
            else {  // statistically ~never; correctness fallback
                int p = atomicAdd(&gcur1[bkt], 1);
                if (p < cap1) ebuf1[(long)bkt * cap1 + p] = pr;
                else { int o = atomicAdd(&govf[0], 1); ovf1[o] = pr; }
            }
        }
        __syncthreads();
        if (tid < NB1) {
            int c = min(lcnt[tid], B1SLOT);
            lbase[tid] = c ? atomicAdd(&gcur1[tid], c) : 0;
        }
        __syncthreads();
        {
            int team = tid >> 5, lane = tid & 31;
            int c = min(lcnt[team], B1SLOT);
            long gb = (long)team * cap1;
            int b0 = lbase[team];
            for (int k = lane; k < c; k += 32) {
                int p = b0 + k;
                if (p < cap1) ebuf1[gb + p] = lbuf[team][k];
                else { int o = atomicAdd(&govf[0], 1); ovf1[o] = lbuf[team][k]; }
            }
        }
        __syncthreads();
        if (tid < NB1) lcnt[tid] = 0;
        __syncthreads();
    }
}

__global__ void k_dinv(const int* __restrict__ deg, float* __restrict__ dinv, int N) {
    int i = blockIdx.x * blockDim.x + threadIdx.x;
    if (i < N) dinv[i] = rsqrtf((float)(1 + deg[i]));
}

// ---- shared GEMM body (permuted packed epilogue store) ----
template<bool A32>
__device__ __forceinline__ void gemm_body(
    const float* __restrict__ X32, const _Float16* __restrict__ X16,
    const _Float16* __restrict__ Wt, const float* __restrict__ dinv,
    _Float16* __restrict__ Y, int M, int K, int NC,
    _Float16 (*As)[40], _Float16 (*Bs)[40], int bx, int by)
{
    const int bn = bx * 128;
    const int bm = by * 128;
    const int tid = threadIdx.x;
    const int w = tid >> 6, l = tid & 63;
    const int wm = (w >> 1) * 64, wn = (w & 1) * 64;
    const int lr = l & 15, lg = l >> 4;

    f32x4 acc[4][4];
    #pragma unroll
    for (int i = 0; i < 4; i++)
        #pragma unroll
        for (int j = 0; j < 4; j++)
            acc[i][j] = (f32x4){0.f, 0.f, 0.f, 0.f};

    for (int k0 = 0; k0 < K; k0 += 32) {
        if (A32) {
            #pragma unroll
            for (int p = 0; p < 2; p++) {
                int rowi = p * 64 + (tid >> 2);
                int colA = (tid & 3) * 8;
                int gm = bm + rowi; if (gm >= M) gm = M - 1;
                float4 f0 = *reinterpret_cast<const float4*>(&X32[(long)gm * K + k0 + colA]);
                float4 f1 = *reinterpret_cast<const float4*>(&X32[(long)gm * K + k0 + colA + 4]);
                h8 hv;
                hv[0] = (_Float16)f0.x; hv[1] = (_Float16)f0.y;
                hv[2] = (_Float16)f0.z; hv[3] = (_Float16)f0.w;
                hv[4] = (_Float16)f1.x; hv[5] = (_Float16)f1.y;
                hv[6] = (_Float16)f1.z; hv[7] = (_Float16)f1.w;
                *reinterpret_cast<h8*>(&As[rowi][colA]) = hv;
            }
        } else {
            int rowi = tid >> 1;
            int colA = (tid & 1) * 16;
            int gm = bm + rowi; if (gm >= M) gm = M - 1;
            *reinterpret_cast<h8*>(&As[rowi][colA]) =
                *reinterpret_cast<const h8*>(&X16[(long)gm * K + k0 + colA]);
            *reinterpret_cast<h8*>(&As[rowi][colA + 8]) =
                *reinterpret_cast<const h8*>(&X16[(long)gm * K + k0 + colA + 8]);
        }
        {
            int n = tid >> 1;
            int colB = (tid & 1) * 16;
            *reinterpret_cast<h8*>(&Bs[n][colB]) =
                *reinterpret_cast<const h8*>(&Wt[(long)(bn + n) * K + k0 + colB]);
            *reinterpret_cast<h8*>(&Bs[n][colB + 8]) =
                *reinterpret_cast<const h8*>(&Wt[(long)(bn + n) * K + k0 + colB + 8]);
        }
        __syncthreads();

        h8 a[4], b[4];
        #pragma unroll
        for (int i = 0; i < 4; i++)
            a[i] = *reinterpret_cast<const h8*>(&As[wm + i * 16 + lr][lg * 8]);
        #pragma unroll
        for (int j = 0; j < 4; j++)
            b[j] = *reinterpret_cast<const h8*>(&Bs[wn + j * 16 + lr][lg * 8]);
        #pragma unroll
        for (int i = 0; i < 4; i++)
            #pragma unroll
            for (int j = 0; j < 4; j++)
                acc[i][j] = __builtin_amdgcn_mfma_f32_16x16x32_f16(
                    a[i], b[j], acc[i][j], 0, 0, 0);
        __syncthreads();
    }

    // permuted store: orig col bn+wn+fn*16+lr -> bn + lr*8 + wn/16 + fn
    // the 4 fn values are consecutive -> one packed 8B h4 store per (fm,r)
    #pragma unroll
    for (int i = 0; i < 4; i++) {
        #pragma unroll
        for (int r = 0; r < 4; r++) {
            int gm = bm + wm + i * 16 + lg * 4 + r;
            if (gm < M) {
                float s = dinv[gm];
                h4 p;
                #pragma unroll
                for (int j = 0; j < 4; j++) p[j] = (_Float16)(acc[i][j][r] * s);
                *reinterpret_cast<h4*>(&Y[(long)gm * NC + bn + (lr << 3) + (wn >> 4)]) = p;
            }
        }
    }
}

struct B2S {
    int2 buf[FBPC][B2SLOT];
    int  cnt[FBPC];
};

// Fused: blocks [0,nfb) = level-2 bucketing (64-way per coarse, 32+-chunk
// flushes -> line-granular); rest = GEMM1 tiles.
__global__ __launch_bounds__(256) void k_b2g(
    const int2* __restrict__ ebuf1, const int* __restrict__ gcur1, int cap1,
    const int2* __restrict__ ovf1, const int* __restrict__ govf,
    int* __restrict__ gcur2, int2* __restrict__ ebuf2, int cap2,
    int2* __restrict__ ovf2, int* __restrict__ govfw,
    int bdiv1, int nfb,
    const float* __restrict__ X32, const _Float16* __restrict__ Wt,
    const float* __restrict__ dinv, _Float16* __restrict__ Y,
    int M, int K, int NC, int gx)
{
    __shared__ __align__(16) char smem[sizeof(B2S) > 20480 ? sizeof(B2S) : 20480];
    const int tid = threadIdx.x;
    if ((int)blockIdx.x < nfb) {
        B2S& S = *reinterpret_cast<B2S*>(smem);
        int cb = blockIdx.x >> 5;       // 32 blocks per coarse bucket
        int li = blockIdx.x & 31;
        int cbase = cb * bdiv1;
        int cnt = min(gcur1[cb], cap1);
        if (tid < FBPC) S.cnt[tid] = 0;
        __syncthreads();
        long e1 = (long)cb * cap1;
        for (int i0 = li * 256; i0 < cnt; i0 += 32 * 256) {
            int e = i0 + tid;
            if (e < cnt) {
                int2 pr = ebuf1[e1 + e];
                int fbl = (unsigned)(pr.y - cbase) / NPB;
                int ls = atomicAdd(&S.cnt[fbl], 1);
                if (ls < B2SLOT) S.buf[fbl][ls] = pr;
                else {
                    int gb2 = (cb << 6) + fbl;
                    int p = atomicAdd(&gcur2[gb2], 1);
                    if (p < cap2) ebuf2[(long)gb2 * cap2 + p] = pr;
                    else { int o = atomicAdd(&govfw[1], 1); ovf2[o] = pr; }
                }
            }
            __syncthreads();
            {
                int team = tid >> 2, lane = tid & 3;
                int c = min(S.cnt[team], B2SLOT);
                int doit = (c >= 32);
                int b0 = 0;
                if (doit && lane == 0) b0 = atomicAdd(&gcur2[(cb << 6) + team], c);
                b0 = __shfl(b0, (tid & 63) & ~3, 64);
                if (doit) {
                    long gb = (long)((cb << 6) + team) * cap2;
                    for (int k = lane; k < c; k += 4) {
                        int p = b0 + k;
                        if (p < cap2) ebuf2[gb + p] = S.buf[team][k];
                        else { int o = atomicAdd(&govfw[1], 1); ovf2[o] = S.buf[team][k]; }
                    }
                }
            }
            __syncthreads();
            if (tid < FBPC && min(S.cnt[tid], B2SLOT) >= 32) S.cnt[tid] = 0;
            __syncthreads();
        }
        {   // residual flush
            int team = tid >> 2, lane = tid & 3;
            int c = min(S.cnt[team], B2SLOT);
            int b0 = 0;
            if (c > 0 && lane == 0) b0 = atomicAdd(&gcur2[(cb << 6) + team], c);
            b0 = __shfl(b0, (tid & 63) & ~3, 64);
            if (c > 0) {
                long gb = (long)((cb << 6) + team) * cap2;
                for (int k = lane; k < c; k += 4) {
                    int p = b0 + k;
                    if (p < cap2) ebuf2[gb + p] = S.buf[team][k];
                    else { int o = atomicAdd(&govfw[1], 1); ovf2[o] = S.buf[team][k]; }
                }
            }
        }
        if (li == 0) {  // drain level-1 overflow (normally empty)
            int no = govf[0];
            for (int i = tid; i < no; i += 256) {
                int2 pr = ovf1[i];
                if ((unsigned)(pr.y - cbase) < (unsigned)bdiv1) {
                    int fbl = (unsigned)(pr.y - cbase) / NPB;
                    int gb2 = (cb << 6) + fbl;
                    int p = atomicAdd(&gcur2[gb2], 1);
                    if (p < cap2) ebuf2[(long)gb2 * cap2 + p] = pr;
                    else { int o = atomicAdd(&govfw[1], 1); ovf2[o] = pr; }
                }
            }
        }
        return;
    }
    int gb = blockIdx.x - nfb;
    _Float16 (*As)[40] = reinterpret_cast<_Float16(*)[40]>(smem);
    _Float16 (*Bs)[40] = reinterpret_cast<_Float16(*)[40]>(smem + 128 * 40 * 2);
    gemm_body<true>(X32, nullptr, Wt, dinv, Y, M, K, NC, As, Bs, gb % gx, gb / gx);
}

__global__ __launch_bounds__(256) void k_gemm16(
    const _Float16* __restrict__ X16, const _Float16* __restrict__ Wt,
    const float* __restrict__ dinv, _Float16* __restrict__ Y, int M, int K, int NC)
{
    __shared__ _Float16 As[128][40];
    __shared__ _Float16 Bs[128][40];
    gemm_body<false>(nullptr, X16, Wt, dinv, Y, M, K, NC, As, Bs, blockIdx.x, blockIdx.y);
}

// One block per fine bucket (x2 feature-halves for layer 1).
// LDS fp32 accumulator [NPB][NST]; edges streamed, gathered 16B/lane,
// accumulated with conflict-free ds_add (permuted storage); self-loop,
// dinv, bias, relu fused at writeout.
template<bool F16OUT, bool RELU>
__global__ __launch_bounds__(256) void k_agg(
    const int* __restrict__ gcur2, const int2* __restrict__ ebuf2, int cap2,
    const int2* __restrict__ ovf2, const int* __restrict__ govf2,
    const _Float16* __restrict__ Y, const float* __restrict__ dinv,
    const float* __restrict__ bias, int N, int FT,
    float* __restrict__ out32, _Float16* __restrict__ out16)
{
    __shared__ float acc[NPB * NST];
    const int fb = blockIdx.x & (NB2 - 1);
    const int fo = (blockIdx.x >> 9) << 7;   // 0 or 128
    const int base = fb * NPB;
    if (base >= N) return;
    const int tid = threadIdx.x;

    float4* az = reinterpret_cast<float4*>(acc);
    for (int i = tid; i < NPB * NST / 4; i += 256)
        az[i] = make_float4(0.f, 0.f, 0.f, 0.f);
    __syncthreads();

    const int w = tid >> 6, s = (tid >> 4) & 3, r = tid & 15;
    const int cnt = min(gcur2[fb], cap2);
    const long eb = (long)fb * cap2;
    int e = w * 4 + s;
    for (; e + 16 < cnt; e += 32) {
        int2 p0 = ebuf2[eb + e];
        int2 p1 = ebuf2[eb + e + 16];
        h8 v0 = *reinterpret_cast<const h8*>(&Y[(long)p0.x * FT + fo + r * 8]);
        h8 v1 = *reinterpret_cast<const h8*>(&Y[(long)p1.x * FT + fo + r * 8]);
        int a0 = (p0.y - base) * NST + r;
        int a1 = (p1.y - base) * NST + r;
        #pragma unroll
        for (int j = 0; j < 8; j++) atomicAdd(&acc[a0 + 16 * j], (float)v0[j]);
        #pragma unroll
        for (int j = 0; j < 8; j++) atomicAdd(&acc[a1 + 16 * j], (float)v1[j]);
    }
    for (; e < cnt; e += 16) {
        int2 p0 = ebuf2[eb + e];
        h8 v0 = *reinterpret_cast<const h8*>(&Y[(long)p0.x * FT + fo + r * 8]);
        int a0 = (p0.y - base) * NST + r;
        #pragma unroll
        for (int j = 0; j < 8; j++) atomicAdd(&acc[a0 + 16 * j], (float)v0[j]);
    }
    {   // bucket-capacity overflow edges (normally zero)
        int no = *govf2;
        for (int i = w * 4 + s; i < no; i += 16) {
            int2 pr = ovf2[i];
            if ((unsigned)(pr.y - base) < (unsigned)NPB) {
                h8 v = *reinterpret_cast<const h8*>(&Y[(long)pr.x * FT + fo + r * 8]);
                int a = (pr.y - base) * NST + r;
                #pragma unroll
                for (int j = 0; j < 8; j++) atomicAdd(&acc[a + 16 * j], (float)v[j]);
            }
        }
    }
    __syncthreads();

    for (int n0 = w * 4 + s; n0 < NPB; n0 += 16) {
        int n = base + n0;
        if (n >= N) break;
        float dn = dinv[n];
        h8 self = *reinterpret_cast<const h8*>(&Y[(long)n * FT + fo + r * 8]);
        float vals[8];
        #pragma unroll
        for (int j = 0; j < 8; j++)
            vals[j] = acc[n0 * NST + 16 * j + r] + (float)self[j];
        if (F16OUT) {
            const float4* bp = reinterpret_cast<const float4*>(&bias[fo + r * 8]);
            float4 blo = bp[0], bhi = bp[1];
            float o8[8] = {
                fmaf(dn, vals[0], blo.x), fmaf(dn, vals[1], blo.y),
                fmaf(dn, vals[2], blo.z), fmaf(dn, vals[3], blo.w),
                fmaf(dn, vals[4], bhi.x), fmaf(dn, vals[5], bhi.y),
                fmaf(dn, vals[6], bhi.z), fmaf(dn, vals[7], bhi.w) };
            h8 o;
            #pragma unroll
            for (int j = 0; j < 8; j++) {
                float v = RELU ? fmaxf(o8[j], 0.f) : o8[j];
                o[j] = (_Float16)v;
            }
            *reinterpret_cast<h8*>(&out16[(long)n * FT + fo + r * 8]) = o;
        } else {
            #pragma unroll
            for (int j = 0; j < 8; j++) {
                float v = fmaf(dn, vals[j], bias[16 * j + r]);
                out32[(long)n * FT + 16 * j + r] = v;   // un-permute
            }
        }
    }
}

extern "C" void kernel_launch(void* const* d_in, const int* in_sizes, int n_in,
                              void* d_out, int out_size, void* d_ws, size_t ws_size,
                              hipStream_t stream)
{
    const float* x   = (const float*)d_in[0];
    const int*   ei  = (const int*)d_in[1];
    const float* W1  = (const float*)d_in[2];
    const float* b1  = (const float*)d_in[3];
    const float* W2  = (const float*)d_in[4];
    const float* b2  = (const float*)d_in[5];

    const int nhid  = in_sizes[3];            // 256
    const int nfeat = in_sizes[5];            // 128
    const int N     = in_sizes[0] / nhid;     // 50000
    const int E     = in_sizes[1] / 2;        // 800000

    const int* row = ei;        // source
    const int* col = ei + E;    // target

    const int bdiv1 = NPB * FBPC;             // 6272 cols per coarse bucket
    const int cap1  = E / NB1 + 65536;
    const int cap2  = 4096;

    size_t cur = 0;
    auto alloc = [&](size_t bytes) {
        void* p = (char*)d_ws + cur;
        cur += (bytes + 255) & ~(size_t)255;
        return p;
    };
    float*     dinv   = (float*)alloc((size_t)N * 4);
    int*       deg_i  = (int*)alloc((size_t)N * 4);
    int*       gcur1  = (int*)alloc((size_t)NB1 * 4);
    int*       gcur2  = (int*)alloc((size_t)NB2 * 4);
    int*       govf   = (int*)alloc(2 * 4);             // [0]=ovf1 cnt, [1]=ovf2 cnt
    int2*      ebuf1  = (int2*)alloc((size_t)NB1 * cap1 * 8);
    int2*      ovf1   = (int2*)alloc((size_t)E * 8);
    int2*      ebuf2  = (int2*)alloc((size_t)NB2 * cap2 * 8);
    int2*      ovf2   = (int2*)alloc((size_t)E * 8);
    _Float16*  wt1    = (_Float16*)alloc((size_t)nhid * nhid * 2);
    _Float16*  wt2    = (_Float16*)alloc((size_t)nhid * nfeat * 2);
    float*     bperm1 = (float*)alloc((size_t)nhid * 4);
    _Float16*  y16    = (_Float16*)alloc((size_t)N * nhid * 2);
    _Float16*  h16    = (_Float16*)alloc((size_t)N * nhid * 2);
    _Float16*  y2     = (_Float16*)alloc((size_t)N * nfeat * 2);
    float*     out    = (float*)d_out;
    (void)ws_size; (void)n_in; (void)out_size;

    const int T = 256;
    const int zb = (N + T - 1) / T;

    // init + weight prep
    {
        int pb = (nhid * (nhid + nfeat) + T - 1) / T;
        k_init<<<zb + pb, T, 0, stream>>>(deg_i, gcur1, gcur2, govf, N,
                                          W1, W2, b1, wt1, wt2, bperm1,
                                          nhid, nhid, nfeat, zb);
    }
    // level-1 bucket + degree histogram
    k_bucket1<<<1024, T, 0, stream>>>(row, col, E, bdiv1, deg_i, gcur1,
                                      ebuf1, cap1, ovf1, govf);
    k_dinv<<<zb, T, 0, stream>>>(deg_i, dinv, N);

    // fused: level-2 bucketing (256 blocks) || GEMM1 tiles
    {
        const int nfb = 256;
        int gx = nhid / 128;
        int gy = (N + 127) / 128;
        k_b2g<<<nfb + gx * gy, T, 0, stream>>>(
            ebuf1, gcur1, cap1, ovf1, govf,
            gcur2, ebuf2, cap2, ovf2, govf,
            bdiv1, nfb,
            x, wt1, dinv, y16, N, nhid, nhid, gx);
    }

    // layer-1 aggregation: both feature-halves in one launch
    k_agg<true, true><<<2 * NB2, T, 0, stream>>>(
        gcur2, ebuf2, cap2, ovf2, govf + 1,
        y16, dinv, bperm1, N, nhid, nullptr, h16);

    // layer 2
    {
        dim3 grid(nfeat / 128, (N + 127) / 128);
        k_gemm16<<<grid, T, 0, stream>>>(h16, wt2, dinv, y2, N, nhid, nfeat);
    }
    k_agg<false, false><<<NB2, T, 0, stream>>>(
        gcur2, ebuf2, cap2, ovf2, govf + 1,
        y2, dinv, b2, N, nfeat, out, nullptr);
}

// Round 9
// 211.620 us; speedup vs baseline: 8.0711x; 8.0711x over previous
//
#include <hip/hip_runtime.h>
#include <math.h>

// ---------------------------------------------------------------------------
// 2-layer GCN:  out = gcn(relu(gcn(x, W1, b1)), W2, b2)
// gcn(x,W,b)[c] = dinv[c] * ( y[c] + sum_{edges r->c} y[r] ) + b
//   where y[r] = dinv[r] * (x[r] @ W),  dinv = rsqrt(1 + indeg)
// CSR gather aggregation (feature-split passes); fp16 MFMA GEMM.
// CSR fill is ATOMIC-FREE: k_count records each edge's within-node rank
// (the atomicAdd return), fill = rowptr[c] + rank[e]. Fill fused with GEMM1.
// ---------------------------------------------------------------------------

typedef _Float16 h8 __attribute__((ext_vector_type(8)));
typedef float    f32x4 __attribute__((ext_vector_type(4)));

// init: zero deg (blocks [0,zb)) + both weight transposes (rest)
__global__ void k_init(int* __restrict__ deg, int N,
                       const float* __restrict__ W1, const float* __restrict__ W2,
                       _Float16* __restrict__ wt1, _Float16* __restrict__ wt2,
                       int K, int n1, int n2, int zb)
{
    if ((int)blockIdx.x < zb) {
        int i = blockIdx.x * blockDim.x + threadIdx.x;
        if (i < N) deg[i] = 0;
    } else {
        int i = (blockIdx.x - zb) * blockDim.x + threadIdx.x;
        int c1 = K * n1;
        if (i < c1) {
            int k = i / n1, n = i % n1;
            wt1[(long)n * K + k] = (_Float16)W1[i];
        } else if (i < c1 + K * n2) {
            int j = i - c1;
            int k = j / n2, n = j % n2;
            wt2[(long)n * K + k] = (_Float16)W2[j];
        }
    }
}

// degree histogram; atomicAdd's return value = edge's rank within its node
__global__ void k_count(const int* __restrict__ col, int E,
                        int* __restrict__ deg, int* __restrict__ rank) {
    int i = blockIdx.x * blockDim.x + threadIdx.x;
    int s = gridDim.x * blockDim.x;
    for (int e = i; e < E; e += s) rank[e] = atomicAdd(&deg[col[e]], 1);
}

// --- 3-phase exclusive scan of deg[N] -> rowptr[N+1] (dinv fused in ph3) ---
__global__ __launch_bounds__(1024) void k_scan1(const int* __restrict__ deg, int N,
                                                int* __restrict__ incl, int* __restrict__ bsum) {
    __shared__ int sm[1024];
    int t = threadIdx.x;
    int i = blockIdx.x * 1024 + t;
    sm[t] = (i < N) ? deg[i] : 0;
    __syncthreads();
    for (int off = 1; off < 1024; off <<= 1) {
        int add = (t >= off) ? sm[t - off] : 0;
        __syncthreads();
        sm[t] += add;
        __syncthreads();
    }
    incl[i] = sm[t];
    if (t == 1023) bsum[blockIdx.x] = sm[t];
}

__global__ void k_scan2(const int* __restrict__ bsum, int* __restrict__ boff, int nb) {
    if (threadIdx.x == 0 && blockIdx.x == 0) {
        int run = 0;
        for (int b = 0; b < nb; b++) { boff[b] = run; run += bsum[b]; }
    }
}

__global__ void k_scan3(const int* __restrict__ incl, const int* __restrict__ boff,
                        const int* __restrict__ deg, int N,
                        int* __restrict__ rowptr, float* __restrict__ dinv) {
    int i = blockIdx.x * blockDim.x + threadIdx.x;
    if (i < N) {
        rowptr[i + 1] = incl[i] + boff[i >> 10];
        dinv[i] = rsqrtf((float)(1 + deg[i]));
    }
    if (i == 0) rowptr[0] = 0;
}

// ---- shared GEMM body ----
// Y[m][n] = fp16( dinv[m] * sum_k X[m][k] * Wt[n][k] )
// 128x128 block tile, BK=32, 4 waves (2x2), each wave 64x64 via 4x4
// mfma_f32_16x16x32_f16 fragments. A32: read X as fp32, convert in staging.
template<bool A32>
__device__ __forceinline__ void gemm_body(
    const float* __restrict__ X32, const _Float16* __restrict__ X16,
    const _Float16* __restrict__ Wt, const float* __restrict__ dinv,
    _Float16* __restrict__ Y, int M, int K, int NC, int bx, int by)
{
    __shared__ _Float16 As[128][40];  // row stride 80B (16B-aligned)
    __shared__ _Float16 Bs[128][40];

    const int bn = bx * 128;
    const int bm = by * 128;
    const int tid = threadIdx.x;
    const int w = tid >> 6, l = tid & 63;
    const int wm = (w >> 1) * 64, wn = (w & 1) * 64;
    const int lr = l & 15, lg = l >> 4;

    f32x4 acc[4][4];
    #pragma unroll
    for (int i = 0; i < 4; i++)
        #pragma unroll
        for (int j = 0; j < 4; j++)
            acc[i][j] = (f32x4){0.f, 0.f, 0.f, 0.f};

    for (int k0 = 0; k0 < K; k0 += 32) {
        if (A32) {
            #pragma unroll
            for (int p = 0; p < 2; p++) {
                int rowi = p * 64 + (tid >> 2);
                int colA = (tid & 3) * 8;
                int gm = bm + rowi; if (gm >= M) gm = M - 1;
                float4 f0 = *reinterpret_cast<const float4*>(&X32[(long)gm * K + k0 + colA]);
                float4 f1 = *reinterpret_cast<const float4*>(&X32[(long)gm * K + k0 + colA + 4]);
                h8 hv;
                hv[0] = (_Float16)f0.x; hv[1] = (_Float16)f0.y;
                hv[2] = (_Float16)f0.z; hv[3] = (_Float16)f0.w;
                hv[4] = (_Float16)f1.x; hv[5] = (_Float16)f1.y;
                hv[6] = (_Float16)f1.z; hv[7] = (_Float16)f1.w;
                *reinterpret_cast<h8*>(&As[rowi][colA]) = hv;
            }
        } else {
            int rowi = tid >> 1;
            int colA = (tid & 1) * 16;
            int gm = bm + rowi; if (gm >= M) gm = M - 1;
            *reinterpret_cast<h8*>(&As[rowi][colA]) =
                *reinterpret_cast<const h8*>(&X16[(long)gm * K + k0 + colA]);
            *reinterpret_cast<h8*>(&As[rowi][colA + 8]) =
                *reinterpret_cast<const h8*>(&X16[(long)gm * K + k0 + colA + 8]);
        }
        {
            int n = tid >> 1;
            int colB = (tid & 1) * 16;
            *reinterpret_cast<h8*>(&Bs[n][colB]) =
                *reinterpret_cast<const h8*>(&Wt[(long)(bn + n) * K + k0 + colB]);
            *reinterpret_cast<h8*>(&Bs[n][colB + 8]) =
                *reinterpret_cast<const h8*>(&Wt[(long)(bn + n) * K + k0 + colB + 8]);
        }
        __syncthreads();

        h8 a[4], b[4];
        #pragma unroll
        for (int i = 0; i < 4; i++)
            a[i] = *reinterpret_cast<const h8*>(&As[wm + i * 16 + lr][lg * 8]);
        #pragma unroll
        for (int j = 0; j < 4; j++)
            b[j] = *reinterpret_cast<const h8*>(&Bs[wn + j * 16 + lr][lg * 8]);
        #pragma unroll
        for (int i = 0; i < 4; i++)
            #pragma unroll
            for (int j = 0; j < 4; j++)
                acc[i][j] = __builtin_amdgcn_mfma_f32_16x16x32_f16(
                    a[i], b[j], acc[i][j], 0, 0, 0);
        __syncthreads();
    }

    // C layout: row = (l>>4)*4 + reg, col = l&15
    #pragma unroll
    for (int i = 0; i < 4; i++) {
        #pragma unroll
        for (int r = 0; r < 4; r++) {
            int gm = bm + wm + i * 16 + lg * 4 + r;
            if (gm < M) {
                float s = dinv[gm];
                #pragma unroll
                for (int j = 0; j < 4; j++)
                    Y[(long)gm * NC + bn + wn + j * 16 + lr] =
                        (_Float16)(acc[i][j][r] * s);
            }
        }
    }
}

// Fused: blocks [0,nfb) do the atomic-free CSR fill; the rest GEMM1 tiles.
__global__ __launch_bounds__(256) void k_fill_gemm(
    const int* __restrict__ row, const int* __restrict__ col,
    const int* __restrict__ rank, int E,
    const int* __restrict__ rowptr, int* __restrict__ srcidx,
    int nfb,
    const float* __restrict__ X32, const _Float16* __restrict__ Wt,
    const float* __restrict__ dinv, _Float16* __restrict__ Y,
    int M, int K, int NC, int gx)
{
    if ((int)blockIdx.x < nfb) {
        int i = blockIdx.x * blockDim.x + threadIdx.x;
        int s = nfb * blockDim.x;
        for (int e = i; e < E; e += s) {
            int c = col[e];
            srcidx[rowptr[c] + rank[e]] = row[e];   // no atomics
        }
        return;
    }
    int gb = blockIdx.x - nfb;
    gemm_body<true>(X32, nullptr, Wt, dinv, Y, M, K, NC, gb % gx, gb / gx);
}

__global__ __launch_bounds__(256) void k_gemm16(
    const _Float16* __restrict__ X16, const _Float16* __restrict__ Wt,
    const float* __restrict__ dinv, _Float16* __restrict__ Y,
    int M, int K, int NC)
{
    gemm_body<false>(nullptr, X16, Wt, dinv, Y, M, K, NC, blockIdx.x, blockIdx.y);
}

// out[node][fo : fo+128] = act( dinv*(Y[node]+sum_e Y[srcidx[e]]) + bias )
// One wave per node. LPR lanes cover the feature slice (16B/lane);
// G = 64/LPR edges per batch, 4-batch unroll -> 4G edges in flight.
template<int LPR, bool F16OUT, bool RELU>
__global__ __launch_bounds__(256) void k_agg(
    const int* __restrict__ rowptr, const int* __restrict__ srcidx,
    const _Float16* __restrict__ Y, const float* __restrict__ dinv,
    const float* __restrict__ bias, int N, int FT, int fo,
    float* __restrict__ out32, _Float16* __restrict__ out16)
{
    const int G = 64 / LPR;   // edges per batch
    int node = blockIdx.x * 4 + (threadIdx.x >> 6);
    if (node >= N) return;
    int lane = threadIdx.x & 63;
    int sub = lane / LPR;
    int fl  = lane % LPR;
    const int fcol = fo + fl * 8;

    float acc[8];
    if (sub == 0) {  // self loop handled by subgroup 0
        h8 v = *reinterpret_cast<const h8*>(&Y[(long)node * FT + fcol]);
        #pragma unroll
        for (int j = 0; j < 8; j++) acc[j] = (float)v[j];
    } else {
        #pragma unroll
        for (int j = 0; j < 8; j++) acc[j] = 0.f;
    }

    int beg = rowptr[node], end = rowptr[node + 1];
    int cnt = end - beg;
    int i = beg + sub;
    int full = cnt / (4 * G);
    for (int t = 0; t < full; t++) {
        int r0 = srcidx[i];
        int r1 = srcidx[i + G];
        int r2 = srcidx[i + 2 * G];
        int r3 = srcidx[i + 3 * G];
        h8 v0 = *reinterpret_cast<const h8*>(&Y[(long)r0 * FT + fcol]);
        h8 v1 = *reinterpret_cast<const h8*>(&Y[(long)r1 * FT + fcol]);
        h8 v2 = *reinterpret_cast<const h8*>(&Y[(long)r2 * FT + fcol]);
        h8 v3 = *reinterpret_cast<const h8*>(&Y[(long)r3 * FT + fcol]);
        #pragma unroll
        for (int j = 0; j < 8; j++)
            acc[j] += ((float)v0[j] + (float)v1[j]) + ((float)v2[j] + (float)v3[j]);
        i += 4 * G;
    }
    for (; i < end; i += G) {
        int r = srcidx[i];
        h8 v = *reinterpret_cast<const h8*>(&Y[(long)r * FT + fcol]);
        #pragma unroll
        for (int j = 0; j < 8; j++) acc[j] += (float)v[j];
    }

    // merge sub-groups
    #pragma unroll
    for (int m = LPR; m < 64; m <<= 1)
        #pragma unroll
        for (int j = 0; j < 8; j++)
            acc[j] += __shfl_xor(acc[j], m, 64);

    float s = dinv[node];
    const float4* b4 = reinterpret_cast<const float4*>(&bias[fcol]);
    float4 blo = b4[0], bhi = b4[1];
    float r8[8];
    r8[0] = fmaf(s, acc[0], blo.x); r8[1] = fmaf(s, acc[1], blo.y);
    r8[2] = fmaf(s, acc[2], blo.z); r8[3] = fmaf(s, acc[3], blo.w);
    r8[4] = fmaf(s, acc[4], bhi.x); r8[5] = fmaf(s, acc[5], bhi.y);
    r8[6] = fmaf(s, acc[6], bhi.z); r8[7] = fmaf(s, acc[7], bhi.w);
    if (RELU) {
        #pragma unroll
        for (int j = 0; j < 8; j++) r8[j] = fmaxf(r8[j], 0.f);
    }

    long base = (long)node * FT + fcol;
    if (F16OUT) {
        if (sub == 0) {
            h8 o;
            #pragma unroll
            for (int j = 0; j < 8; j++) o[j] = (_Float16)r8[j];
            *reinterpret_cast<h8*>(&out16[base]) = o;
        }
    } else {
        if (sub == 0) {
            *reinterpret_cast<float4*>(&out32[base]) =
                make_float4(r8[0], r8[1], r8[2], r8[3]);
        } else if (sub == 1) {
            *reinterpret_cast<float4*>(&out32[base + 4]) =
                make_float4(r8[4], r8[5], r8[6], r8[7]);
        }
    }
}

extern "C" void kernel_launch(void* const* d_in, const int* in_sizes, int n_in,
                              void* d_out, int out_size, void* d_ws, size_t ws_size,
                              hipStream_t stream)
{
    const float* x   = (const float*)d_in[0];
    const int*   ei  = (const int*)d_in[1];
    const float* W1  = (const float*)d_in[2];
    const float* b1  = (const float*)d_in[3];
    const float* W2  = (const float*)d_in[4];
    const float* b2  = (const float*)d_in[5];

    const int nhid  = in_sizes[3];            // 256
    const int nfeat = in_sizes[5];            // 128
    const int N     = in_sizes[0] / nhid;     // 50000
    const int E     = in_sizes[1] / 2;        // 800000

    const int* row = ei;        // source
    const int* col = ei + E;    // target

    const int nb = (N + 1023) / 1024;

    size_t cur = 0;
    auto alloc = [&](size_t bytes) {
        void* p = (char*)d_ws + cur;
        cur += (bytes + 255) & ~(size_t)255;
        return p;
    };
    float*     dinv   = (float*)alloc((size_t)N * 4);
    int*       deg_i  = (int*)alloc((size_t)N * 4);
    int*       rank   = (int*)alloc((size_t)E * 4);
    int*       rowptr = (int*)alloc((size_t)(N + 1) * 4);
    int*       incl   = (int*)alloc((size_t)nb * 1024 * 4);
    int*       bsum   = (int*)alloc((size_t)nb * 4);
    int*       boff   = (int*)alloc((size_t)nb * 4);
    int*       srcidx = (int*)alloc((size_t)E * 4);
    _Float16*  wt1    = (_Float16*)alloc((size_t)nhid * nhid * 2);
    _Float16*  wt2    = (_Float16*)alloc((size_t)nhid * nfeat * 2);
    _Float16*  y16    = (_Float16*)alloc((size_t)N * nhid * 2);   // layer-1 y
    _Float16*  h16    = (_Float16*)alloc((size_t)N * nhid * 2);   // relu output
    _Float16*  y2     = (_Float16*)alloc((size_t)N * nfeat * 2);  // layer-2 y
    float*     out    = (float*)d_out;
    (void)ws_size; (void)n_in; (void)out_size;

    const int T = 256;

    // ---- init (zero deg + weight transposes, one launch) ----
    {
        int zb = (N + T - 1) / T;
        int pb = (nhid * (nhid + nfeat) + T - 1) / T;
        k_init<<<zb + pb, T, 0, stream>>>(deg_i, N, W1, W2, wt1, wt2,
                                          nhid, nhid, nfeat, zb);
    }
    // ---- CSR build (count records ranks; fill is atomic-free) ----
    k_count<<<1024, T, 0, stream>>>(col, E, deg_i, rank);
    k_scan1<<<nb, 1024, 0, stream>>>(deg_i, N, incl, bsum);
    k_scan2<<<1, 64, 0, stream>>>(bsum, boff, nb);
    k_scan3<<<(N + T - 1) / T, T, 0, stream>>>(incl, boff, deg_i, N, rowptr, dinv);

    // ---- fused: CSR fill (512 blocks) || GEMM1 tiles ----
    {
        const int nfb = 512;
        int gx = nhid / 128;
        int gy = (N + 127) / 128;
        k_fill_gemm<<<nfb + gx * gy, T, 0, stream>>>(
            row, col, rank, E, rowptr, srcidx, nfb,
            x, wt1, dinv, y16, N, nhid, nhid, gx);
    }

    // ---- layer 1 aggregation: two feature-half passes ----
    k_agg<16, true, true><<<(N + 3) / 4, T, 0, stream>>>(
        rowptr, srcidx, y16, dinv, b1, N, nhid, 0, nullptr, h16);
    k_agg<16, true, true><<<(N + 3) / 4, T, 0, stream>>>(
        rowptr, srcidx, y16, dinv, b1, N, nhid, 128, nullptr, h16);

    // ---- layer 2 ----
    {
        dim3 grid(nfeat / 128, (N + 127) / 128);
        k_gemm16<<<grid, T, 0, stream>>>(h16, wt2, dinv, y2, N, nhid, nfeat);
    }
    k_agg<16, false, false><<<(N + 3) / 4, T, 0, stream>>>(
        rowptr, srcidx, y2, dinv, b2, N, nfeat, 0, out, nullptr);
}

// Round 10
// 180.536 us; speedup vs baseline: 9.4607x; 1.1722x over previous
//
#include <hip/hip_runtime.h>
#include <math.h>

// ---------------------------------------------------------------------------
// 2-layer GCN:  out = gcn(relu(gcn(x, W1, b1)), W2, b2)
// gcn(x,W,b)[c] = dinv[c] * ( dinv[c]*xw[c] + sum_{edges r->c} dinv[r]*xw[r] ) + b
//   where xw = x @ W (UNSCALED in y buffers), dinv = rsqrt(1 + indeg)
// No scan: fixed-capacity CSR slots (srcidx[c*CAP + rank[e]]), rank = return
// of the degree-count atomicAdd. count fused with GEMM1 (GEMM1 is unscaled ->
// independent of degrees). GEMM K-loop is register-prefetch pipelined.
// ---------------------------------------------------------------------------

typedef _Float16 h8 __attribute__((ext_vector_type(8)));
typedef float    f32x4 __attribute__((ext_vector_type(4)));

#define CAP 64   // slots per node; overflow list handles adversarial degrees

// init: zero deg/govf (blocks [0,zb)) + both weight transposes (rest)
__global__ void k_init(int* __restrict__ deg, int* __restrict__ govf, int N,
                       const float* __restrict__ W1, const float* __restrict__ W2,
                       _Float16* __restrict__ wt1, _Float16* __restrict__ wt2,
                       int K, int n1, int n2, int zb)
{
    if ((int)blockIdx.x < zb) {
        int i = blockIdx.x * blockDim.x + threadIdx.x;
        if (i < N) deg[i] = 0;
        if (blockIdx.x == 0 && threadIdx.x == 0) *govf = 0;
    } else {
        int i = (blockIdx.x - zb) * blockDim.x + threadIdx.x;
        int c1 = K * n1;
        if (i < c1) {
            int k = i / n1, n = i % n1;
            wt1[(long)n * K + k] = (_Float16)W1[i];
        } else if (i < c1 + K * n2) {
            int j = i - c1;
            int k = j / n2, n = j % n2;
            wt2[(long)n * K + k] = (_Float16)W2[j];
        }
    }
}

// ---- shared GEMM body (register-prefetch pipelined, UNSCALED output) ----
// Y[m][n] = fp16( sum_k X[m][k] * Wt[n][k] )
// 128x128 block tile, BK=32, 4 waves (2x2), each wave 64x64 via 4x4
// mfma_f32_16x16x32_f16 fragments. A32: read X as fp32, convert at commit.
template<bool A32>
__device__ __forceinline__ void gemm_body(
    const float* __restrict__ X32, const _Float16* __restrict__ X16,
    const _Float16* __restrict__ Wt, _Float16* __restrict__ Y,
    int M, int K, int NC, int bx, int by)
{
    __shared__ _Float16 As[128][40];  // row stride 80B (16B-aligned)
    __shared__ _Float16 Bs[128][40];

    const int bn = bx * 128;
    const int bm = by * 128;
    const int tid = threadIdx.x;
    const int w = tid >> 6, l = tid & 63;
    const int wm = (w >> 1) * 64, wn = (w & 1) * 64;
    const int lr = l & 15, lg = l >> 4;

    const int arow = tid >> 2, acol = (tid & 3) * 8;   // A32 loader
    const int xrow = tid >> 1, xcol = (tid & 1) * 16;  // fp16 A / B loader

    f32x4 acc[4][4];
    #pragma unroll
    for (int i = 0; i < 4; i++)
        #pragma unroll
        for (int j = 0; j < 4; j++)
            acc[i][j] = (f32x4){0.f, 0.f, 0.f, 0.f};

    float4 pf0, pf1, pf2, pf3;   // A32 prefetch regs
    h8 pa0, pa1;                 // fp16-A prefetch regs
    h8 pb0, pb1;                 // B prefetch regs

    auto loadA = [&](int k0) {
        if (A32) {
            int gm0 = bm + arow;      if (gm0 >= M) gm0 = M - 1;
            int gm1 = bm + 64 + arow; if (gm1 >= M) gm1 = M - 1;
            pf0 = *reinterpret_cast<const float4*>(&X32[(long)gm0 * K + k0 + acol]);
            pf1 = *reinterpret_cast<const float4*>(&X32[(long)gm0 * K + k0 + acol + 4]);
            pf2 = *reinterpret_cast<const float4*>(&X32[(long)gm1 * K + k0 + acol]);
            pf3 = *reinterpret_cast<const float4*>(&X32[(long)gm1 * K + k0 + acol + 4]);
        } else {
            int gm = bm + xrow; if (gm >= M) gm = M - 1;
            pa0 = *reinterpret_cast<const h8*>(&X16[(long)gm * K + k0 + xcol]);
            pa1 = *reinterpret_cast<const h8*>(&X16[(long)gm * K + k0 + xcol + 8]);
        }
    };
    auto loadB = [&](int k0) {
        pb0 = *reinterpret_cast<const h8*>(&Wt[(long)(bn + xrow) * K + k0 + xcol]);
        pb1 = *reinterpret_cast<const h8*>(&Wt[(long)(bn + xrow) * K + k0 + xcol + 8]);
    };

    loadA(0); loadB(0);
    for (int k0 = 0; k0 < K; k0 += 32) {
        // commit staged regs to LDS
        if (A32) {
            h8 h0, h1;
            h0[0] = (_Float16)pf0.x; h0[1] = (_Float16)pf0.y;
            h0[2] = (_Float16)pf0.z; h0[3] = (_Float16)pf0.w;
            h0[4] = (_Float16)pf1.x; h0[5] = (_Float16)pf1.y;
            h0[6] = (_Float16)pf1.z; h0[7] = (_Float16)pf1.w;
            h1[0] = (_Float16)pf2.x; h1[1] = (_Float16)pf2.y;
            h1[2] = (_Float16)pf2.z; h1[3] = (_Float16)pf2.w;
            h1[4] = (_Float16)pf3.x; h1[5] = (_Float16)pf3.y;
            h1[6] = (_Float16)pf3.z; h1[7] = (_Float16)pf3.w;
            *reinterpret_cast<h8*>(&As[arow][acol]) = h0;
            *reinterpret_cast<h8*>(&As[64 + arow][acol]) = h1;
        } else {
            *reinterpret_cast<h8*>(&As[xrow][xcol]) = pa0;
            *reinterpret_cast<h8*>(&As[xrow][xcol + 8]) = pa1;
        }
        *reinterpret_cast<h8*>(&Bs[xrow][xcol]) = pb0;
        *reinterpret_cast<h8*>(&Bs[xrow][xcol + 8]) = pb1;
        __syncthreads();

        // prefetch next K-tile while computing this one
        if (k0 + 32 < K) { loadA(k0 + 32); loadB(k0 + 32); }

        h8 a[4], b[4];
        #pragma unroll
        for (int i = 0; i < 4; i++)
            a[i] = *reinterpret_cast<const h8*>(&As[wm + i * 16 + lr][lg * 8]);
        #pragma unroll
        for (int j = 0; j < 4; j++)
            b[j] = *reinterpret_cast<const h8*>(&Bs[wn + j * 16 + lr][lg * 8]);
        #pragma unroll
        for (int i = 0; i < 4; i++)
            #pragma unroll
            for (int j = 0; j < 4; j++)
                acc[i][j] = __builtin_amdgcn_mfma_f32_16x16x32_f16(
                    a[i], b[j], acc[i][j], 0, 0, 0);
        __syncthreads();
    }

    // C layout: row = (l>>4)*4 + reg, col = l&15 ; unscaled store
    #pragma unroll
    for (int i = 0; i < 4; i++) {
        #pragma unroll
        for (int r = 0; r < 4; r++) {
            int gm = bm + wm + i * 16 + lg * 4 + r;
            if (gm < M) {
                #pragma unroll
                for (int j = 0; j < 4; j++)
                    Y[(long)gm * NC + bn + wn + j * 16 + lr] =
                        (_Float16)acc[i][j][r];
            }
        }
    }
}

// Fused: blocks [0,ncb) do the degree count (recording ranks); rest = GEMM1.
__global__ __launch_bounds__(256) void k_count_gemm(
    const int* __restrict__ col, int E, int* __restrict__ deg, int* __restrict__ rank,
    int ncb,
    const float* __restrict__ X32, const _Float16* __restrict__ Wt,
    _Float16* __restrict__ Y, int M, int K, int NC, int gx)
{
    if ((int)blockIdx.x < ncb) {
        int i = blockIdx.x * blockDim.x + threadIdx.x;
        int s = ncb * blockDim.x;
        for (int e = i; e < E; e += s) rank[e] = atomicAdd(&deg[col[e]], 1);
        return;
    }
    int gb = blockIdx.x - ncb;
    gemm_body<true>(X32, nullptr, Wt, Y, M, K, NC, gb % gx, gb / gx);
}

// Fused: blocks [0,zb) compute dinv; the rest do the atomic-free slot fill.
__global__ __launch_bounds__(256) void k_fill_dinv(
    const int* __restrict__ row, const int* __restrict__ col,
    const int* __restrict__ rank, int E,
    const int* __restrict__ deg, float* __restrict__ dinv, int N,
    int* __restrict__ srcidx, int2* __restrict__ ovf, int* __restrict__ govf,
    int zb)
{
    if ((int)blockIdx.x < zb) {
        int i = blockIdx.x * blockDim.x + threadIdx.x;
        if (i < N) dinv[i] = rsqrtf(1.f + (float)deg[i]);
        return;
    }
    int g = (blockIdx.x - zb) * blockDim.x + threadIdx.x;
    int nthreads = (gridDim.x - zb) * blockDim.x;
    if ((E & 3) == 0) {
        int G4 = E >> 2;
        for (int q = g; q < G4; q += nthreads) {
            int e = q << 2;
            int4 c4 = *reinterpret_cast<const int4*>(&col[e]);
            int4 r4 = *reinterpret_cast<const int4*>(&row[e]);
            int4 k4 = *reinterpret_cast<const int4*>(&rank[e]);
            if (k4.x < CAP) srcidx[c4.x * CAP + k4.x] = r4.x;
            else { int o = atomicAdd(govf, 1); ovf[o] = make_int2(r4.x, c4.x); }
            if (k4.y < CAP) srcidx[c4.y * CAP + k4.y] = r4.y;
            else { int o = atomicAdd(govf, 1); ovf[o] = make_int2(r4.y, c4.y); }
            if (k4.z < CAP) srcidx[c4.z * CAP + k4.z] = r4.z;
            else { int o = atomicAdd(govf, 1); ovf[o] = make_int2(r4.z, c4.z); }
            if (k4.w < CAP) srcidx[c4.w * CAP + k4.w] = r4.w;
            else { int o = atomicAdd(govf, 1); ovf[o] = make_int2(r4.w, c4.w); }
        }
    } else {
        for (int e = g; e < E; e += nthreads) {
            int c = col[e], r = row[e], k = rank[e];
            if (k < CAP) srcidx[c * CAP + k] = r;
            else { int o = atomicAdd(govf, 1); ovf[o] = make_int2(r, c); }
        }
    }
}

__global__ __launch_bounds__(256) void k_gemm16(
    const _Float16* __restrict__ X16, const _Float16* __restrict__ Wt,
    _Float16* __restrict__ Y, int M, int K, int NC)
{
    gemm_body<false>(nullptr, X16, Wt, Y, M, K, NC, blockIdx.x, blockIdx.y);
}

// out[node][fo:fo+128] = act( dc*( dc*Y[node] + sum_e dinv[r]*Y[r] ) + bias )
// One wave per node, slot-CSR. LPR lanes per row slice (16B/lane);
// G = 64/LPR edges per batch, 4-batch unroll.
template<int LPR, bool F16OUT, bool RELU>
__global__ __launch_bounds__(256) void k_agg(
    const int* __restrict__ deg, const float* __restrict__ dinv,
    const int* __restrict__ srcidx,
    const int2* __restrict__ ovf, const int* __restrict__ govf,
    const _Float16* __restrict__ Y, const float* __restrict__ bias,
    int N, int FT, int fo,
    float* __restrict__ out32, _Float16* __restrict__ out16)
{
    const int G = 64 / LPR;   // edges per batch
    int node = blockIdx.x * 4 + (threadIdx.x >> 6);
    if (node >= N) return;
    int lane = threadIdx.x & 63;
    int sub = lane / LPR;
    int fl  = lane % LPR;
    const int fcol = fo + fl * 8;

    float dc = dinv[node];
    int cnt = min(deg[node], CAP);
    const int beg = node * CAP;

    float acc[8];
    if (sub == 0) {  // self loop (scaled by dc; outer dc applied at the end)
        h8 v = *reinterpret_cast<const h8*>(&Y[(long)node * FT + fcol]);
        #pragma unroll
        for (int j = 0; j < 8; j++) acc[j] = dc * (float)v[j];
    } else {
        #pragma unroll
        for (int j = 0; j < 8; j++) acc[j] = 0.f;
    }

    int i = sub;
    int full = cnt / (4 * G);
    for (int t = 0; t < full; t++) {
        int r0 = srcidx[beg + i];
        int r1 = srcidx[beg + i + G];
        int r2 = srcidx[beg + i + 2 * G];
        int r3 = srcidx[beg + i + 3 * G];
        float d0 = dinv[r0], d1 = dinv[r1], d2 = dinv[r2], d3 = dinv[r3];
        h8 v0 = *reinterpret_cast<const h8*>(&Y[(long)r0 * FT + fcol]);
        h8 v1 = *reinterpret_cast<const h8*>(&Y[(long)r1 * FT + fcol]);
        h8 v2 = *reinterpret_cast<const h8*>(&Y[(long)r2 * FT + fcol]);
        h8 v3 = *reinterpret_cast<const h8*>(&Y[(long)r3 * FT + fcol]);
        #pragma unroll
        for (int j = 0; j < 8; j++)
            acc[j] += (d0 * (float)v0[j] + d1 * (float)v1[j]) +
                      (d2 * (float)v2[j] + d3 * (float)v3[j]);
        i += 4 * G;
    }
    for (; i < cnt; i += G) {
        int r = srcidx[beg + i];
        float d = dinv[r];
        h8 v = *reinterpret_cast<const h8*>(&Y[(long)r * FT + fcol]);
        #pragma unroll
        for (int j = 0; j < 8; j++) acc[j] += d * (float)v[j];
    }
    {   // capacity-overflow edges (normally zero)
        int no = *govf;
        for (int t = sub; t < no; t += G) {
            int2 pr = ovf[t];
            if (pr.y == node) {
                float d = dinv[pr.x];
                h8 v = *reinterpret_cast<const h8*>(&Y[(long)pr.x * FT + fcol]);
                #pragma unroll
                for (int j = 0; j < 8; j++) acc[j] += d * (float)v[j];
            }
        }
    }

    // merge sub-groups
    #pragma unroll
    for (int m = LPR; m < 64; m <<= 1)
        #pragma unroll
        for (int j = 0; j < 8; j++)
            acc[j] += __shfl_xor(acc[j], m, 64);

    const float4* b4 = reinterpret_cast<const float4*>(&bias[fcol]);
    float4 blo = b4[0], bhi = b4[1];
    float r8[8];
    r8[0] = fmaf(dc, acc[0], blo.x); r8[1] = fmaf(dc, acc[1], blo.y);
    r8[2] = fmaf(dc, acc[2], blo.z); r8[3] = fmaf(dc, acc[3], blo.w);
    r8[4] = fmaf(dc, acc[4], bhi.x); r8[5] = fmaf(dc, acc[5], bhi.y);
    r8[6] = fmaf(dc, acc[6], bhi.z); r8[7] = fmaf(dc, acc[7], bhi.w);
    if (RELU) {
        #pragma unroll
        for (int j = 0; j < 8; j++) r8[j] = fmaxf(r8[j], 0.f);
    }

    long base = (long)node * FT + fcol;
    if (F16OUT) {
        if (sub == 0) {
            h8 o;
            #pragma unroll
            for (int j = 0; j < 8; j++) o[j] = (_Float16)r8[j];
            *reinterpret_cast<h8*>(&out16[base]) = o;
        }
    } else {
        if (sub == 0) {
            *reinterpret_cast<float4*>(&out32[base]) =
                make_float4(r8[0], r8[1], r8[2], r8[3]);
        } else if (sub == 1) {
            *reinterpret_cast<float4*>(&out32[base + 4]) =
                make_float4(r8[4], r8[5], r8[6], r8[7]);
        }
    }
}

extern "C" void kernel_launch(void* const* d_in, const int* in_sizes, int n_in,
                              void* d_out, int out_size, void* d_ws, size_t ws_size,
                              hipStream_t stream)
{
    const float* x   = (const float*)d_in[0];
    const int*   ei  = (const int*)d_in[1];
    const float* W1  = (const float*)d_in[2];
    const float* b1  = (const float*)d_in[3];
    const float* W2  = (const float*)d_in[4];
    const float* b2  = (const float*)d_in[5];

    const int nhid  = in_sizes[3];            // 256
    const int nfeat = in_sizes[5];            // 128
    const int N     = in_sizes[0] / nhid;     // 50000
    const int E     = in_sizes[1] / 2;        // 800000

    const int* row = ei;        // source
    const int* col = ei + E;    // target

    size_t cur = 0;
    auto alloc = [&](size_t bytes) {
        void* p = (char*)d_ws + cur;
        cur += (bytes + 255) & ~(size_t)255;
        return p;
    };
    float*     dinv   = (float*)alloc((size_t)N * 4);
    int*       deg_i  = (int*)alloc((size_t)N * 4);
    int*       rank   = (int*)alloc((size_t)E * 4);
    int*       srcidx = (int*)alloc((size_t)N * CAP * 4);
    int2*      ovf    = (int2*)alloc((size_t)E * 8);
    int*       govf   = (int*)alloc(256);
    _Float16*  wt1    = (_Float16*)alloc((size_t)nhid * nhid * 2);
    _Float16*  wt2    = (_Float16*)alloc((size_t)nhid * nfeat * 2);
    _Float16*  y16    = (_Float16*)alloc((size_t)N * nhid * 2);   // xw (unscaled)
    _Float16*  h16    = (_Float16*)alloc((size_t)N * nhid * 2);   // relu output
    _Float16*  y2     = (_Float16*)alloc((size_t)N * nfeat * 2);  // hw (unscaled)
    float*     out    = (float*)d_out;
    (void)ws_size; (void)n_in; (void)out_size;

    const int T = 256;
    const int zb = (N + T - 1) / T;

    // ---- init (zero deg + weight transposes, one launch) ----
    {
        int pb = (nhid * (nhid + nfeat) + T - 1) / T;
        k_init<<<zb + pb, T, 0, stream>>>(deg_i, govf, N, W1, W2, wt1, wt2,
                                          nhid, nhid, nfeat, zb);
    }

    // ---- fused: degree count + rank (256 blocks) || GEMM1 (unscaled) ----
    {
        const int ncb = 256;
        int gx = nhid / 128;
        int gy = (N + 127) / 128;
        k_count_gemm<<<ncb + gx * gy, T, 0, stream>>>(
            col, E, deg_i, rank, ncb, x, wt1, y16, N, nhid, nhid, gx);
    }

    // ---- fused: dinv (zb blocks) || atomic-free slot fill ----
    k_fill_dinv<<<zb + 1024, T, 0, stream>>>(
        row, col, rank, E, deg_i, dinv, N, srcidx, ovf, govf, zb);

    // ---- layer 1 aggregation: two feature-half passes ----
    k_agg<16, true, true><<<(N + 3) / 4, T, 0, stream>>>(
        deg_i, dinv, srcidx, ovf, govf, y16, b1, N, nhid, 0, nullptr, h16);
    k_agg<16, true, true><<<(N + 3) / 4, T, 0, stream>>>(
        deg_i, dinv, srcidx, ovf, govf, y16, b1, N, nhid, 128, nullptr, h16);

    // ---- layer 2 ----
    {
        dim3 grid(nfeat / 128, (N + 127) / 128);
        k_gemm16<<<grid, T, 0, stream>>>(h16, wt2, y2, N, nhid, nfeat);
    }
    k_agg<16, false, false><<<(N + 3) / 4, T, 0, stream>>>(
        deg_i, dinv, srcidx, ovf, govf, y2, b2, N, nfeat, 0, out, nullptr);
}